// Round 1
// baseline (727.201 us; speedup 1.0000x reference)
//
#include <hip/hip_runtime.h>
#include <hip/hip_bf16.h>

typedef unsigned short ushort_t;
typedef __attribute__((ext_vector_type(8))) short short8;
typedef __attribute__((ext_vector_type(4))) short short4v;
typedef __attribute__((ext_vector_type(4))) float f32x4;

__device__ __forceinline__ float bf2f(unsigned short u) {
    union { unsigned int i; float f; } v; v.i = ((unsigned int)u) << 16; return v.f;
}
__device__ __forceinline__ unsigned short f2bf(float f) {
    union { float f; unsigned int i; } v; v.f = f;
    unsigned int r = v.i + 0x7fffu + ((v.i >> 16) & 1u);
    return (unsigned short)(r >> 16);
}

#define TILE_M 128
#define TILE_N 128
#define TILE_K 64
#define LDT 72   // padded LDS stride (bf16 elems): 2-way bank conflict max (free)

// C[M,N] = A[M,K] @ B[N,K]^T (+bias). A f32 or bf16; B always f32; C f32 or bf16.
template<int A_F32, int HAS_BIAS, int OUT_F32>
__global__ __launch_bounds__(256) void gemm_bt(
    const void* __restrict__ Ap, const float* __restrict__ B,
    const float* __restrict__ bias, void* __restrict__ Cp,
    int M, int N, int K)
{
    __shared__ short As[TILE_M * LDT];
    __shared__ short Bs[TILE_N * LDT];
    const int tid  = threadIdx.x;
    const int lane = tid & 63;
    const int wave = tid >> 6;
    const int wr = wave >> 1, wc = wave & 1;
    const int lo = lane & 15, hi = lane >> 4;
    const int rowBase = blockIdx.y * TILE_M;
    const int colBase = blockIdx.x * TILE_N;

    f32x4 acc[4][4] = {};

    for (int k0 = 0; k0 < K; k0 += TILE_K) {
        #pragma unroll
        for (int p = 0; p < 8; ++p) {
            int idx = (p * 256 + tid) * 4;
            int r = idx >> 6, c = idx & 63;
            short4v sv;
            if (A_F32) {
                const float* A = (const float*)Ap;
                f32x4 v = *(const f32x4*)&A[(size_t)(rowBase + r) * K + k0 + c];
                sv[0] = (short)f2bf(v[0]); sv[1] = (short)f2bf(v[1]);
                sv[2] = (short)f2bf(v[2]); sv[3] = (short)f2bf(v[3]);
            } else {
                const short* A = (const short*)Ap;
                sv = *(const short4v*)&A[(size_t)(rowBase + r) * K + k0 + c];
            }
            *(short4v*)&As[r * LDT + c] = sv;
            f32x4 w = *(const f32x4*)&B[(size_t)(colBase + r) * K + k0 + c];
            short4v sw;
            sw[0] = (short)f2bf(w[0]); sw[1] = (short)f2bf(w[1]);
            sw[2] = (short)f2bf(w[2]); sw[3] = (short)f2bf(w[3]);
            *(short4v*)&Bs[r * LDT + c] = sw;
        }
        __syncthreads();
        #pragma unroll
        for (int s = 0; s < 2; ++s) {
            short8 a[4], b[4];
            #pragma unroll
            for (int i = 0; i < 4; ++i)
                a[i] = *(const short8*)&As[(wr * 64 + i * 16 + lo) * LDT + s * 32 + hi * 8];
            #pragma unroll
            for (int j = 0; j < 4; ++j)
                b[j] = *(const short8*)&Bs[(wc * 64 + j * 16 + lo) * LDT + s * 32 + hi * 8];
            #pragma unroll
            for (int i = 0; i < 4; ++i)
                #pragma unroll
                for (int j = 0; j < 4; ++j)
                    acc[i][j] = __builtin_amdgcn_mfma_f32_16x16x32_bf16(a[i], b[j], acc[i][j], 0, 0, 0);
        }
        __syncthreads();
    }

    #pragma unroll
    for (int i = 0; i < 4; ++i) {
        int rowA = rowBase + wr * 64 + i * 16 + hi * 4;
        #pragma unroll
        for (int j = 0; j < 4; ++j) {
            int col = colBase + wc * 64 + j * 16 + lo;
            float bv = HAS_BIAS ? bias[col] : 0.0f;
            #pragma unroll
            for (int r = 0; r < 4; ++r) {
                float v = acc[i][j][r] + bv;
                if (OUT_F32) ((float*)Cp)[(size_t)(rowA + r) * N + col] = v;
                else         ((unsigned short*)Cp)[(size_t)(rowA + r) * N + col] = f2bf(v);
            }
        }
    }
}

// In-place RoPE over rows of [nrows, 512] bf16; pos = row % 2048.
// theta_i = 10000^(-2*(i-1)/512)  (faithful to reference's (i-1))
__global__ __launch_bounds__(256) void rope_kernel(unsigned short* __restrict__ T)
{
    int gid = blockIdx.x * 256 + threadIdx.x;
    int row = gid >> 6;          // 64 threads per row (8 elems each)
    int seg = (gid & 63) * 8;
    int pos = row & 2047;
    short8 v = *(short8*)&T[(size_t)row * 512 + seg];
    const float THC = -0.05190512648261308f;  // -2*log2(10000)/512
    #pragma unroll
    for (int p = 0; p < 4; ++p) {
        int i = (seg >> 1) + p;
        float theta = exp2f(THC * ((float)i - 1.0f));
        float ang = (float)pos * theta;
        float sn, cs;
        sincosf(ang, &sn, &cs);
        float e = bf2f((unsigned short)v[2 * p]);
        float o = bf2f((unsigned short)v[2 * p + 1]);
        v[2 * p]     = (short)f2bf(e * cs + o * sn);
        v[2 * p + 1] = (short)f2bf(-e * sn + o * cs);
    }
    *(short8*)&T[(size_t)row * 512 + seg] = v;
}

// Causal flash attention. Q/K/V/O: [8*2048, 512] bf16, head h cols h*64..h*64+63.
// grid (32 qblocks, 64 bh), 256 threads = 4 waves; wave w owns q rows qb*64+w*16..+15.
__global__ __launch_bounds__(256) void attn_kernel(
    const unsigned short* __restrict__ Q, const unsigned short* __restrict__ K,
    const unsigned short* __restrict__ V, unsigned short* __restrict__ O)
{
    const int tid  = threadIdx.x;
    const int lane = tid & 63;
    const int wave = tid >> 6;
    const int qb = blockIdx.x;
    const int bh = blockIdx.y;
    const int bb = bh >> 3, hh = bh & 7;
    const int lo = lane & 15, hi = lane >> 4;

    __shared__ short P[4][16 * 72];

    const size_t baseRow = (size_t)bb * 2048;
    const int colBase = hh * 64;
    const int qrow = qb * 64 + wave * 16;

    short8 aq[2];
    #pragma unroll
    for (int s = 0; s < 2; ++s)
        aq[s] = *(const short8*)&Q[(baseRow + qrow + lo) * 512 + colBase + s * 32 + hi * 8];

    f32x4 o_acc[4] = {};
    float m_i[4], l_i[4];
    #pragma unroll
    for (int r = 0; r < 4; ++r) { m_i[r] = -1e30f; l_i[r] = 0.0f; }

    for (int kb = 0; kb <= qb; ++kb) {
        f32x4 s_acc[4] = {};
        #pragma unroll
        for (int s = 0; s < 2; ++s)
            #pragma unroll
            for (int n = 0; n < 4; ++n) {
                short8 bk = *(const short8*)&K[(baseRow + kb * 64 + n * 16 + lo) * 512 + colBase + s * 32 + hi * 8];
                s_acc[n] = __builtin_amdgcn_mfma_f32_16x16x32_bf16(aq[s], bk, s_acc[n], 0, 0, 0);
            }

        float sv[4][4];
        #pragma unroll
        for (int n = 0; n < 4; ++n) {
            int key = kb * 64 + n * 16 + lo;
            #pragma unroll
            for (int r = 0; r < 4; ++r) {
                float x = s_acc[n][r] * 0.125f;
                if (kb == qb) {
                    int qr = qrow + hi * 4 + r;
                    if (key > qr) x = -1e30f;
                }
                sv[n][r] = x;
            }
        }

        float alpha[4];
        #pragma unroll
        for (int r = 0; r < 4; ++r) {
            float x = fmaxf(fmaxf(sv[0][r], sv[1][r]), fmaxf(sv[2][r], sv[3][r]));
            #pragma unroll
            for (int off = 1; off < 16; off <<= 1) x = fmaxf(x, __shfl_xor(x, off));
            float mn = fmaxf(m_i[r], x);
            alpha[r] = __expf(m_i[r] - mn);
            m_i[r] = mn;
        }
        #pragma unroll
        for (int n = 0; n < 4; ++n)
            #pragma unroll
            for (int r = 0; r < 4; ++r)
                sv[n][r] = __expf(sv[n][r] - m_i[r]);

        #pragma unroll
        for (int r = 0; r < 4; ++r) {
            float x = sv[0][r] + sv[1][r] + sv[2][r] + sv[3][r];
            #pragma unroll
            for (int off = 1; off < 16; off <<= 1) x += __shfl_xor(x, off);
            l_i[r] = l_i[r] * alpha[r] + x;
        }
        #pragma unroll
        for (int t = 0; t < 4; ++t)
            #pragma unroll
            for (int r = 0; r < 4; ++r)
                o_acc[t][r] *= alpha[r];

        #pragma unroll
        for (int n = 0; n < 4; ++n)
            #pragma unroll
            for (int r = 0; r < 4; ++r)
                P[wave][(hi * 4 + r) * 72 + n * 16 + lo] = (short)f2bf(sv[n][r]);

        #pragma unroll
        for (int s = 0; s < 2; ++s) {
            short8 ap = *(const short8*)&P[wave][lo * 72 + s * 32 + hi * 8];
            #pragma unroll
            for (int t = 0; t < 4; ++t) {
                short8 bv;
                #pragma unroll
                for (int e = 0; e < 8; ++e)
                    bv[e] = (short)V[(baseRow + kb * 64 + s * 32 + hi * 8 + e) * 512 + colBase + t * 16 + lo];
                o_acc[t] = __builtin_amdgcn_mfma_f32_16x16x32_bf16(ap, bv, o_acc[t], 0, 0, 0);
            }
        }
    }

    #pragma unroll
    for (int t = 0; t < 4; ++t)
        #pragma unroll
        for (int r = 0; r < 4; ++r) {
            float v = o_acc[t][r] / l_i[r];
            O[(baseRow + qrow + hi * 4 + r) * 512 + colBase + t * 16 + lo] = f2bf(v);
        }
}

extern "C" void kernel_launch(void* const* d_in, const int* in_sizes, int n_in,
                              void* d_out, int out_size, void* d_ws, size_t ws_size,
                              hipStream_t stream)
{
    (void)in_sizes; (void)n_in; (void)out_size; (void)ws_size;
    const float* x   = (const float*)d_in[0];
    const float* w_q = (const float*)d_in[1];
    const float* w_k = (const float*)d_in[2];
    const float* w_v = (const float*)d_in[3];
    const float* ipw = (const float*)d_in[4];
    const float* ipb = (const float*)d_in[5];
    const float* ow  = (const float*)d_in[6];
    const float* ob  = (const float*)d_in[7];

    const int M = 16384, D = 512;
    const size_t SZ = (size_t)M * D;
    unsigned short* T  = (unsigned short*)d_ws;   // 3 contiguous [M,D] bf16 buffers
    unsigned short* Qb = T + 3 * SZ;
    unsigned short* Kb = T + 4 * SZ;
    unsigned short* Vb = T + 5 * SZ;
    unsigned short* Cb = T + 6 * SZ;

    dim3 blk(256);
    dim3 gg(D / TILE_N, M / TILE_M);

    // Stage 1: T = x @ w^T (f32 in, bf16 out)
    gemm_bt<1, 0, 0><<<gg, blk, 0, stream>>>(x, w_q, nullptr, T,          M, D, D);
    gemm_bt<1, 0, 0><<<gg, blk, 0, stream>>>(x, w_k, nullptr, T + SZ,     M, D, D);
    gemm_bt<1, 0, 0><<<gg, blk, 0, stream>>>(x, w_v, nullptr, T + 2 * SZ, M, D, D);

    // Stage 2: RoPE in-place over all 3*M rows (pos = row % 2048 holds across buffers)
    rope_kernel<<<dim3(3 * M * 64 / 256), blk, 0, stream>>>(T);

    // Stage 3: in_proj with bias (bf16 in, bf16 out)
    gemm_bt<0, 1, 0><<<gg, blk, 0, stream>>>(T,          ipw,               ipb,        Qb, M, D, D);
    gemm_bt<0, 1, 0><<<gg, blk, 0, stream>>>(T + SZ,     ipw + 512 * 512,   ipb + 512,  Kb, M, D, D);
    gemm_bt<0, 1, 0><<<gg, blk, 0, stream>>>(T + 2 * SZ, ipw + 2 * 512 * 512, ipb + 1024, Vb, M, D, D);

    // Stage 4: causal flash attention
    attn_kernel<<<dim3(32, 64), blk, 0, stream>>>(Qb, Kb, Vb, Cb);

    // Stage 5: output projection (bf16 in, f32 out, bias)
    gemm_bt<0, 1, 1><<<gg, blk, 0, stream>>>(Cb, ow, ob, (float*)d_out, M, D, D);
}

// Round 2
// 705.767 us; speedup vs baseline: 1.0304x; 1.0304x over previous
//
#include <hip/hip_runtime.h>
#include <hip/hip_bf16.h>

typedef __attribute__((ext_vector_type(8))) short short8;
typedef __attribute__((ext_vector_type(4))) short short4v;
typedef __attribute__((ext_vector_type(4))) float f32x4;

__device__ __forceinline__ float bf2f(unsigned short u) {
    union { unsigned int i; float f; } v; v.i = ((unsigned int)u) << 16; return v.f;
}
__device__ __forceinline__ unsigned short f2bf(float f) {
    union { float f; unsigned int i; } v; v.f = f;
    unsigned int r = v.i + 0x7fffu + ((v.i >> 16) & 1u);
    return (unsigned short)(r >> 16);
}

#define TILE_M 128
#define TILE_N 128
#define TILE_K 64
#define LDT 72   // padded LDS stride (bf16 elems)

// C[M,N] = A[M,K] @ B[N,K]^T (+bias). A f32 or bf16; B always f32.
// OUT: 0 = bf16 row-major, 1 = f32 row-major, 2 = bf16 transposed-V layout
//      Vt[(b*8+h)*64 + d][m] with d = col&63, h = col>>6, b = row>>11, m = row&2047.
template<int A_F32, int HAS_BIAS, int OUT>
__global__ __launch_bounds__(256) void gemm_bt(
    const void* __restrict__ Ap, const float* __restrict__ B,
    const float* __restrict__ bias, void* __restrict__ Cp,
    int M, int N, int K)
{
    __shared__ short As[TILE_M * LDT];
    __shared__ short Bs[TILE_N * LDT];
    const int tid  = threadIdx.x;
    const int lane = tid & 63;
    const int wave = tid >> 6;
    const int wr = wave >> 1, wc = wave & 1;
    const int lo = lane & 15, hi = lane >> 4;
    const int rowBase = blockIdx.y * TILE_M;
    const int colBase = blockIdx.x * TILE_N;

    f32x4 acc[4][4] = {};

    for (int k0 = 0; k0 < K; k0 += TILE_K) {
        #pragma unroll
        for (int p = 0; p < 8; ++p) {
            int idx = (p * 256 + tid) * 4;
            int r = idx >> 6, c = idx & 63;
            short4v sv;
            if (A_F32) {
                const float* A = (const float*)Ap;
                f32x4 v = *(const f32x4*)&A[(size_t)(rowBase + r) * K + k0 + c];
                sv[0] = (short)f2bf(v[0]); sv[1] = (short)f2bf(v[1]);
                sv[2] = (short)f2bf(v[2]); sv[3] = (short)f2bf(v[3]);
            } else {
                const short* A = (const short*)Ap;
                sv = *(const short4v*)&A[(size_t)(rowBase + r) * K + k0 + c];
            }
            *(short4v*)&As[r * LDT + c] = sv;
            f32x4 w = *(const f32x4*)&B[(size_t)(colBase + r) * K + k0 + c];
            short4v sw;
            sw[0] = (short)f2bf(w[0]); sw[1] = (short)f2bf(w[1]);
            sw[2] = (short)f2bf(w[2]); sw[3] = (short)f2bf(w[3]);
            *(short4v*)&Bs[r * LDT + c] = sw;
        }
        __syncthreads();
        #pragma unroll
        for (int s = 0; s < 2; ++s) {
            short8 a[4], b[4];
            #pragma unroll
            for (int i = 0; i < 4; ++i)
                a[i] = *(const short8*)&As[(wr * 64 + i * 16 + lo) * LDT + s * 32 + hi * 8];
            #pragma unroll
            for (int j = 0; j < 4; ++j)
                b[j] = *(const short8*)&Bs[(wc * 64 + j * 16 + lo) * LDT + s * 32 + hi * 8];
            #pragma unroll
            for (int i = 0; i < 4; ++i)
                #pragma unroll
                for (int j = 0; j < 4; ++j)
                    acc[i][j] = __builtin_amdgcn_mfma_f32_16x16x32_bf16(a[i], b[j], acc[i][j], 0, 0, 0);
        }
        __syncthreads();
    }

    #pragma unroll
    for (int i = 0; i < 4; ++i) {
        int rowA = rowBase + wr * 64 + i * 16 + hi * 4;
        #pragma unroll
        for (int j = 0; j < 4; ++j) {
            int col = colBase + wc * 64 + j * 16 + lo;
            float bv = HAS_BIAS ? bias[col] : 0.0f;
            if (OUT == 2) {
                short4v sv;
                #pragma unroll
                for (int r = 0; r < 4; ++r) sv[r] = (short)f2bf(acc[i][j][r] + bv);
                size_t idx = (((size_t)(rowA >> 11) * 8 + (col >> 6)) * 64 + (col & 63)) * 2048
                             + (rowA & 2047);
                *(short4v*)&((unsigned short*)Cp)[idx] = sv;
            } else {
                #pragma unroll
                for (int r = 0; r < 4; ++r) {
                    float v = acc[i][j][r] + bv;
                    if (OUT == 1) ((float*)Cp)[(size_t)(rowA + r) * N + col] = v;
                    else          ((unsigned short*)Cp)[(size_t)(rowA + r) * N + col] = f2bf(v);
                }
            }
        }
    }
}

// In-place RoPE over rows of [nrows, 512] bf16; pos = row % 2048.
__global__ __launch_bounds__(256) void rope_kernel(unsigned short* __restrict__ T)
{
    int gid = blockIdx.x * 256 + threadIdx.x;
    int row = gid >> 6;
    int seg = (gid & 63) * 8;
    int pos = row & 2047;
    short8 v = *(short8*)&T[(size_t)row * 512 + seg];
    const float THC = -0.05190512648261308f;  // -2*log2(10000)/512
    #pragma unroll
    for (int p = 0; p < 4; ++p) {
        int i = (seg >> 1) + p;
        float theta = exp2f(THC * ((float)i - 1.0f));
        float ang = (float)pos * theta;
        float sn, cs;
        sincosf(ang, &sn, &cs);
        float e = bf2f((unsigned short)v[2 * p]);
        float o = bf2f((unsigned short)v[2 * p + 1]);
        v[2 * p]     = (short)f2bf(e * cs + o * sn);
        v[2 * p + 1] = (short)f2bf(-e * sn + o * cs);
    }
    *(short8*)&T[(size_t)row * 512 + seg] = v;
}

// Causal flash attention. Q/K/O: [16384, 512] bf16 row-major; Vt: [64 bh][64 d][2048 m].
// grid (16 qtiles of 128, 64 bh), 256 threads = 4 waves; wave w owns 32 q rows.
__global__ __launch_bounds__(256) void attn_kernel(
    const unsigned short* __restrict__ Q, const unsigned short* __restrict__ K,
    const unsigned short* __restrict__ Vt, unsigned short* __restrict__ O)
{
    const int tid  = threadIdx.x;
    const int lane = tid & 63;
    const int wave = tid >> 6;
    const int qb = blockIdx.x;
    const int bh = blockIdx.y;
    const int bb = bh >> 3, hh = bh & 7;
    const int lo = lane & 15, hi = lane >> 4;

    __shared__ short P[4][32 * 72];

    const size_t rowQ = (size_t)bb * 2048;
    const int colBase = hh * 64;
    const unsigned short* Vh = Vt + (size_t)bh * 64 * 2048;
    const int qrow = qb * 128 + wave * 32;

    short8 aq[2][2];
    #pragma unroll
    for (int m = 0; m < 2; ++m)
        #pragma unroll
        for (int s = 0; s < 2; ++s)
            aq[m][s] = *(const short8*)&Q[(rowQ + qrow + m * 16 + lo) * 512 + colBase + s * 32 + hi * 8];

    f32x4 o_acc[2][4] = {};
    float m_i[2][4], l_i[2][4];
    #pragma unroll
    for (int m = 0; m < 2; ++m)
        #pragma unroll
        for (int r = 0; r < 4; ++r) { m_i[m][r] = -1e30f; l_i[m][r] = 0.0f; }

    const int kb_max = 2 * qb + (wave >> 1);
    for (int kb = 0; kb <= kb_max; ++kb) {
        f32x4 s_acc[2][4] = {};
        #pragma unroll
        for (int s = 0; s < 2; ++s)
            #pragma unroll
            for (int n = 0; n < 4; ++n) {
                short8 bk = *(const short8*)&K[(rowQ + kb * 64 + n * 16 + lo) * 512 + colBase + s * 32 + hi * 8];
                #pragma unroll
                for (int m = 0; m < 2; ++m)
                    s_acc[m][n] = __builtin_amdgcn_mfma_f32_16x16x32_bf16(aq[m][s], bk, s_acc[m][n], 0, 0, 0);
            }

        const bool need_mask = (kb * 64 + 63 > qrow);
        float sv[2][4][4];
        #pragma unroll
        for (int m = 0; m < 2; ++m)
            #pragma unroll
            for (int n = 0; n < 4; ++n) {
                int key = kb * 64 + n * 16 + lo;
                #pragma unroll
                for (int r = 0; r < 4; ++r) {
                    float x = s_acc[m][n][r] * 0.125f;
                    if (need_mask) {
                        int qr = qrow + m * 16 + hi * 4 + r;
                        if (key > qr) x = -1e30f;
                    }
                    sv[m][n][r] = x;
                }
            }

        float alpha[2][4];
        #pragma unroll
        for (int m = 0; m < 2; ++m)
            #pragma unroll
            for (int r = 0; r < 4; ++r) {
                float x = fmaxf(fmaxf(sv[m][0][r], sv[m][1][r]), fmaxf(sv[m][2][r], sv[m][3][r]));
                #pragma unroll
                for (int off = 1; off < 16; off <<= 1) x = fmaxf(x, __shfl_xor(x, off));
                float mn = fmaxf(m_i[m][r], x);
                alpha[m][r] = __expf(m_i[m][r] - mn);
                m_i[m][r] = mn;
            }
        #pragma unroll
        for (int m = 0; m < 2; ++m)
            #pragma unroll
            for (int n = 0; n < 4; ++n)
                #pragma unroll
                for (int r = 0; r < 4; ++r)
                    sv[m][n][r] = __expf(sv[m][n][r] - m_i[m][r]);

        #pragma unroll
        for (int m = 0; m < 2; ++m)
            #pragma unroll
            for (int r = 0; r < 4; ++r) {
                float x = sv[m][0][r] + sv[m][1][r] + sv[m][2][r] + sv[m][3][r];
                #pragma unroll
                for (int off = 1; off < 16; off <<= 1) x += __shfl_xor(x, off);
                l_i[m][r] = l_i[m][r] * alpha[m][r] + x;
            }
        #pragma unroll
        for (int m = 0; m < 2; ++m)
            #pragma unroll
            for (int t = 0; t < 4; ++t)
                #pragma unroll
                for (int r = 0; r < 4; ++r)
                    o_acc[m][t][r] *= alpha[m][r];

        #pragma unroll
        for (int m = 0; m < 2; ++m)
            #pragma unroll
            for (int n = 0; n < 4; ++n)
                #pragma unroll
                for (int r = 0; r < 4; ++r)
                    P[wave][(m * 16 + hi * 4 + r) * 72 + n * 16 + lo] = (short)f2bf(sv[m][n][r]);

        #pragma unroll
        for (int s = 0; s < 2; ++s) {
            short8 ap[2];
            #pragma unroll
            for (int m = 0; m < 2; ++m)
                ap[m] = *(const short8*)&P[wave][(m * 16 + lo) * 72 + s * 32 + hi * 8];
            #pragma unroll
            for (int t = 0; t < 4; ++t) {
                short8 bv = *(const short8*)&Vh[(t * 16 + lo) * 2048 + kb * 64 + s * 32 + hi * 8];
                #pragma unroll
                for (int m = 0; m < 2; ++m)
                    o_acc[m][t] = __builtin_amdgcn_mfma_f32_16x16x32_bf16(ap[m], bv, o_acc[m][t], 0, 0, 0);
            }
        }
    }

    #pragma unroll
    for (int m = 0; m < 2; ++m)
        #pragma unroll
        for (int t = 0; t < 4; ++t)
            #pragma unroll
            for (int r = 0; r < 4; ++r) {
                float v = o_acc[m][t][r] / l_i[m][r];
                O[(rowQ + qrow + m * 16 + hi * 4 + r) * 512 + colBase + t * 16 + lo] = f2bf(v);
            }
}

extern "C" void kernel_launch(void* const* d_in, const int* in_sizes, int n_in,
                              void* d_out, int out_size, void* d_ws, size_t ws_size,
                              hipStream_t stream)
{
    (void)in_sizes; (void)n_in; (void)out_size; (void)ws_size;
    const float* x   = (const float*)d_in[0];
    const float* w_q = (const float*)d_in[1];
    const float* w_k = (const float*)d_in[2];
    const float* w_v = (const float*)d_in[3];
    const float* ipw = (const float*)d_in[4];
    const float* ipb = (const float*)d_in[5];
    const float* ow  = (const float*)d_in[6];
    const float* ob  = (const float*)d_in[7];

    const int M = 16384, D = 512;
    const size_t SZ = (size_t)M * D;
    unsigned short* T  = (unsigned short*)d_ws;   // 3 contiguous [M,D] bf16 buffers
    unsigned short* Qb = T + 3 * SZ;
    unsigned short* Kb = T + 4 * SZ;
    unsigned short* Vt = T + 5 * SZ;              // transposed V: [64 bh][64 d][2048 m]
    unsigned short* Cb = T + 6 * SZ;

    dim3 blk(256);
    dim3 gg(D / TILE_N, M / TILE_M);

    // Stage 1: T = x @ w^T (f32 in, bf16 out)
    gemm_bt<1, 0, 0><<<gg, blk, 0, stream>>>(x, w_q, nullptr, T,          M, D, D);
    gemm_bt<1, 0, 0><<<gg, blk, 0, stream>>>(x, w_k, nullptr, T + SZ,     M, D, D);
    gemm_bt<1, 0, 0><<<gg, blk, 0, stream>>>(x, w_v, nullptr, T + 2 * SZ, M, D, D);

    // Stage 2: RoPE in-place over all 3*M rows
    rope_kernel<<<dim3(3 * M * 64 / 256), blk, 0, stream>>>(T);

    // Stage 3: in_proj with bias (bf16 in, bf16 out; V written transposed)
    gemm_bt<0, 1, 0><<<gg, blk, 0, stream>>>(T,          ipw,                 ipb,        Qb, M, D, D);
    gemm_bt<0, 1, 0><<<gg, blk, 0, stream>>>(T + SZ,     ipw + 512 * 512,     ipb + 512,  Kb, M, D, D);
    gemm_bt<0, 1, 2><<<gg, blk, 0, stream>>>(T + 2 * SZ, ipw + 2 * 512 * 512, ipb + 1024, Vt, M, D, D);

    // Stage 4: causal flash attention
    attn_kernel<<<dim3(16, 64), blk, 0, stream>>>(Qb, Kb, Vt, Cb);

    // Stage 5: output projection (bf16 in, f32 out, bias)
    gemm_bt<0, 1, 1><<<gg, blk, 0, stream>>>(Cb, ow, ob, (float*)d_out, M, D, D);
}

// Round 7
// 440.528 us; speedup vs baseline: 1.6507x; 1.6021x over previous
//
#include <hip/hip_runtime.h>
#include <hip/hip_bf16.h>

typedef __attribute__((ext_vector_type(8))) short short8;
typedef __attribute__((ext_vector_type(4))) short short4v;
typedef __attribute__((ext_vector_type(4))) float f32x4;

__device__ __forceinline__ float bf2f(unsigned short u) {
    union { unsigned int i; float f; } v; v.i = ((unsigned int)u) << 16; return v.f;
}
__device__ __forceinline__ unsigned short f2bf(float f) {
    union { float f; unsigned int i; } v; v.f = f;
    unsigned int r = v.i + 0x7fffu + ((v.i >> 16) & 1u);
    return (unsigned short)(r >> 16);
}

#define GLDS16(g, l) __builtin_amdgcn_global_load_lds( \
    (const __attribute__((address_space(1))) unsigned int*)(g), \
    (__attribute__((address_space(3))) unsigned int*)(l), 16, 0, 0)

// ---------------- f32 -> bf16 conversion (vectorized) ----------------
__global__ __launch_bounds__(256) void cvt_one(
    const float* __restrict__ in, unsigned short* __restrict__ out, int nchunk)
{
    int i = blockIdx.x * 256 + threadIdx.x;
    if (i >= nchunk) return;
    f32x4 a = *(const f32x4*)&in[(size_t)i * 8];
    f32x4 b = *(const f32x4*)&in[(size_t)i * 8 + 4];
    short8 o;
    o[0] = (short)f2bf(a[0]); o[1] = (short)f2bf(a[1]);
    o[2] = (short)f2bf(a[2]); o[3] = (short)f2bf(a[3]);
    o[4] = (short)f2bf(b[0]); o[5] = (short)f2bf(b[1]);
    o[6] = (short)f2bf(b[2]); o[7] = (short)f2bf(b[3]);
    *(short8*)&out[(size_t)i * 8] = o;
}

// ---------------- bf16 GEMM, m97 structure ----------------
// C[M,N] = A[M,K] @ B[N,K]^T (+bias). A,B bf16 row-major.
// OUT: 0 = bf16 row-major, 1 = f32 row-major, 2 = bf16 transposed-V layout
template<int HAS_BIAS, int OUT>
__global__ __launch_bounds__(256) void gemm_bt(
    const unsigned short* __restrict__ A, const unsigned short* __restrict__ B,
    const float* __restrict__ bias, void* __restrict__ Cp,
    int M, int N, int K)
{
    __shared__ __align__(16) short As[128 * 64];
    __shared__ __align__(16) short Bs[128 * 64];
    const int tid  = threadIdx.x;
    const int lane = tid & 63;
    const int wave = tid >> 6;
    const int wr = wave >> 1, wc = wave & 1;
    const int lo = lane & 15, hi = lane >> 4;
    const int rowBase = blockIdx.y * 128;
    const int colBase = blockIdx.x * 128;

    f32x4 acc[4][4] = {};

    for (int k0 = 0; k0 < K; k0 += 64) {
        const unsigned short* Ab = A + (size_t)rowBase * K + k0;
        const unsigned short* Bb = B + (size_t)colBase * K + k0;
        #pragma unroll
        for (int p = 0; p < 4; ++p) {
            int o = p * 256 + tid;
            GLDS16(&Ab[(size_t)(o >> 3) * K + (o & 7) * 8], &As[o * 8]);
        }
        #pragma unroll
        for (int p = 0; p < 4; ++p) {
            int o = p * 256 + tid;
            GLDS16(&Bb[(size_t)(o >> 3) * K + (o & 7) * 8], &Bs[o * 8]);
        }
        __syncthreads();
        #pragma unroll
        for (int s = 0; s < 2; ++s) {
            short8 a[4], b[4];
            #pragma unroll
            for (int i = 0; i < 4; ++i)
                a[i] = *(const short8*)&As[(wr * 64 + i * 16 + lo) * 64 + s * 32 + hi * 8];
            #pragma unroll
            for (int j = 0; j < 4; ++j)
                b[j] = *(const short8*)&Bs[(wc * 64 + j * 16 + lo) * 64 + s * 32 + hi * 8];
            #pragma unroll
            for (int i = 0; i < 4; ++i)
                #pragma unroll
                for (int j = 0; j < 4; ++j)
                    acc[i][j] = __builtin_amdgcn_mfma_f32_16x16x32_bf16(a[i], b[j], acc[i][j], 0, 0, 0);
        }
        __syncthreads();
    }

    #pragma unroll
    for (int i = 0; i < 4; ++i) {
        int rowA = rowBase + wr * 64 + i * 16 + hi * 4;
        #pragma unroll
        for (int j = 0; j < 4; ++j) {
            int col = colBase + wc * 64 + j * 16 + lo;
            float bv = HAS_BIAS ? bias[col] : 0.0f;
            if (OUT == 2) {
                short4v sv;
                #pragma unroll
                for (int r = 0; r < 4; ++r) sv[r] = (short)f2bf(acc[i][j][r] + bv);
                size_t idx = (((size_t)(rowA >> 11) * 8 + (col >> 6)) * 64 + (col & 63)) * 2048
                             + (rowA & 2047);
                *(short4v*)&((unsigned short*)Cp)[idx] = sv;
            } else {
                #pragma unroll
                for (int r = 0; r < 4; ++r) {
                    float v = acc[i][j][r] + bv;
                    if (OUT == 1) ((float*)Cp)[(size_t)(rowA + r) * N + col] = v;
                    else          ((unsigned short*)Cp)[(size_t)(rowA + r) * N + col] = f2bf(v);
                }
            }
        }
    }
}

// ---------------- RoPE in-place, rows of [*, 512] bf16, pos = row % 2048 ----------------
__global__ __launch_bounds__(256) void rope_kernel(unsigned short* __restrict__ T)
{
    int gid = blockIdx.x * 256 + threadIdx.x;
    int row = gid >> 6;
    int seg = (gid & 63) * 8;
    int pos = row & 2047;
    short8 v = *(short8*)&T[(size_t)row * 512 + seg];
    const float THC = -0.05190512648261308f;  // -2*log2(10000)/512
    #pragma unroll
    for (int p = 0; p < 4; ++p) {
        int i = (seg >> 1) + p;
        float theta = exp2f(THC * ((float)i - 1.0f));
        float ang = (float)pos * theta;
        float sn, cs;
        sincosf(ang, &sn, &cs);
        float e = bf2f((unsigned short)v[2 * p]);
        float o = bf2f((unsigned short)v[2 * p + 1]);
        v[2 * p]     = (short)f2bf(e * cs + o * sn);
        v[2 * p + 1] = (short)f2bf(-e * sn + o * cs);
    }
    *(short8*)&T[(size_t)row * 512 + seg] = v;
}

// ---------------- causal flash attention ----------------
// Q/K/O: [16384, 512] bf16; Vt: [64 bh][64 d][2048 m] bf16.
// Grid (16 pairs, 64 bh), 256 thr = 4 waves. Pair (qa, 31-qa) of 64-row q-tiles:
// waves 0,1 -> tile qa (32 rows each), waves 2,3 -> tile 31-qa. K/V double-buffered
// in LDS (block-wide staging), loads issued 2 iterations ahead, 1 barrier/iter.

__device__ __forceinline__ void attn_step(
    int kt, int kmaxw, int qrow, int lo, int hi,
    const short* __restrict__ KsB, const short* __restrict__ VsB,
    short* __restrict__ Pw,
    short8 (&aq)[2][2], f32x4 (&o_acc)[2][4],
    float (&m_i)[2][4], float (&l_i)[2][4])
{
    if (kt > kmaxw) return;

    f32x4 sa[2][4] = {};
    #pragma unroll
    for (int s = 0; s < 2; ++s) {
        short8 bk[4];
        #pragma unroll
        for (int n = 0; n < 4; ++n)
            bk[n] = *(const short8*)&KsB[(n * 16 + lo) * 72 + s * 32 + hi * 8];
        #pragma unroll
        for (int n = 0; n < 4; ++n) {
            sa[0][n] = __builtin_amdgcn_mfma_f32_16x16x32_bf16(aq[0][s], bk[n], sa[0][n], 0, 0, 0);
            sa[1][n] = __builtin_amdgcn_mfma_f32_16x16x32_bf16(aq[1][s], bk[n], sa[1][n], 0, 0, 0);
        }
    }

    const bool need_mask = (kt == kmaxw);
    float sv[2][4][4];
    #pragma unroll
    for (int m = 0; m < 2; ++m)
        #pragma unroll
        for (int n = 0; n < 4; ++n) {
            int key = kt * 64 + n * 16 + lo;
            #pragma unroll
            for (int r = 0; r < 4; ++r) {
                float x = sa[m][n][r] * 0.125f;
                if (need_mask) {
                    int qr = qrow + m * 16 + hi * 4 + r;
                    if (key > qr) x = -1e30f;
                }
                sv[m][n][r] = x;
            }
        }

    float alpha[2][4];
    #pragma unroll
    for (int m = 0; m < 2; ++m)
        #pragma unroll
        for (int r = 0; r < 4; ++r) {
            float x = fmaxf(fmaxf(sv[m][0][r], sv[m][1][r]), fmaxf(sv[m][2][r], sv[m][3][r]));
            #pragma unroll
            for (int off = 1; off < 16; off <<= 1) x = fmaxf(x, __shfl_xor(x, off));
            float mn = fmaxf(m_i[m][r], x);
            alpha[m][r] = __expf(m_i[m][r] - mn);
            m_i[m][r] = mn;
        }
    #pragma unroll
    for (int m = 0; m < 2; ++m)
        #pragma unroll
        for (int n = 0; n < 4; ++n)
            #pragma unroll
            for (int r = 0; r < 4; ++r)
                sv[m][n][r] = __expf(sv[m][n][r] - m_i[m][r]);

    #pragma unroll
    for (int m = 0; m < 2; ++m)
        #pragma unroll
        for (int r = 0; r < 4; ++r) {
            float x = sv[m][0][r] + sv[m][1][r] + sv[m][2][r] + sv[m][3][r];
            #pragma unroll
            for (int off = 1; off < 16; off <<= 1) x += __shfl_xor(x, off);
            l_i[m][r] = l_i[m][r] * alpha[m][r] + x;
        }
    #pragma unroll
    for (int m = 0; m < 2; ++m)
        #pragma unroll
        for (int t = 0; t < 4; ++t)
            #pragma unroll
            for (int r = 0; r < 4; ++r)
                o_acc[m][t][r] *= alpha[m][r];

    #pragma unroll
    for (int m = 0; m < 2; ++m)
        #pragma unroll
        for (int n = 0; n < 4; ++n)
            #pragma unroll
            for (int r = 0; r < 4; ++r)
                Pw[(m * 16 + hi * 4 + r) * 72 + n * 16 + lo] = (short)f2bf(sv[m][n][r]);

    #pragma unroll
    for (int s = 0; s < 2; ++s) {
        short8 ap[2];
        #pragma unroll
        for (int m = 0; m < 2; ++m)
            ap[m] = *(const short8*)&Pw[(m * 16 + lo) * 72 + s * 32 + hi * 8];
        #pragma unroll
        for (int t = 0; t < 4; ++t) {
            short8 bv = *(const short8*)&VsB[(t * 16 + lo) * 72 + s * 32 + hi * 8];
            #pragma unroll
            for (int m = 0; m < 2; ++m)
                o_acc[m][t] = __builtin_amdgcn_mfma_f32_16x16x32_bf16(ap[m], bv, o_acc[m][t], 0, 0, 0);
        }
    }
}

#define STG_LOAD(kt, KR0, KR1, VR0, VR1) { \
    int rr = tid >> 3, cc = (tid & 7) * 8; \
    KR0 = *(const short8*)&Kp[(rowQ + (size_t)((kt) * 64 + rr)) * 512 + colBase + cc]; \
    KR1 = *(const short8*)&Kp[(rowQ + (size_t)((kt) * 64 + rr + 32)) * 512 + colBase + cc]; \
    VR0 = *(const short8*)&Vh[(size_t)rr * 2048 + (kt) * 64 + cc]; \
    VR1 = *(const short8*)&Vh[(size_t)(rr + 32) * 2048 + (kt) * 64 + cc]; }

#define STG_WRITE(BUF, KR0, KR1, VR0, VR1) { \
    int rr = tid >> 3, cc = (tid & 7) * 8; \
    *(short8*)&Ks[BUF][rr * 72 + cc] = KR0; \
    *(short8*)&Ks[BUF][(rr + 32) * 72 + cc] = KR1; \
    *(short8*)&Vs[BUF][rr * 72 + cc] = VR0; \
    *(short8*)&Vs[BUF][(rr + 32) * 72 + cc] = VR1; }

__global__ __launch_bounds__(256, 2) void attn_kernel(
    const unsigned short* __restrict__ Q, const unsigned short* __restrict__ Kp,
    const unsigned short* __restrict__ Vt, unsigned short* __restrict__ O)
{
    const int tid = threadIdx.x, lane = tid & 63, wave = tid >> 6;
    const int lo = lane & 15, hi = lane >> 4;
    const int qa = blockIdx.x;              // 0..15
    const int qbig = 31 - qa;               // 16..31
    const int bh = blockIdx.y;
    const int bb = bh >> 3, hh = bh & 7;

    const int tileq = (wave >> 1) ? qbig : qa;
    const int qrow  = tileq * 64 + (wave & 1) * 32;
    const int kmaxw = tileq;
    const int KB2   = qbig;                 // block-uniform staging limit

    __shared__ __align__(16) short Ks[2][64 * 72];
    __shared__ __align__(16) short Vs[2][64 * 72];
    __shared__ __align__(16) short P[4][32 * 72];
    short* Pw = P[wave];

    const size_t rowQ = (size_t)bb * 2048;
    const int colBase = hh * 64;
    const unsigned short* Vh = Vt + (size_t)bh * 64 * 2048;

    short8 aq[2][2];
    #pragma unroll
    for (int m = 0; m < 2; ++m)
        #pragma unroll
        for (int s = 0; s < 2; ++s)
            aq[m][s] = *(const short8*)&Q[(rowQ + qrow + m * 16 + lo) * 512 + colBase + s * 32 + hi * 8];

    f32x4 o_acc[2][4] = {};
    float m_i[2][4], l_i[2][4];
    #pragma unroll
    for (int m = 0; m < 2; ++m)
        #pragma unroll
        for (int r = 0; r < 4; ++r) { m_i[m][r] = -1e30f; l_i[m][r] = 0.0f; }

    short8 ka0, ka1, va0, va1;   // slot A (even kt data)
    short8 kb0, kb1, vb0, vb1;   // slot B (odd kt data)

    STG_LOAD(0, ka0, ka1, va0, va1);
    STG_WRITE(0, ka0, ka1, va0, va1);
    STG_LOAD(1, kb0, kb1, vb0, vb1);        // KB2 >= 16 always
    __syncthreads();

    for (int kt = 0; kt <= KB2; ) {
        // even step: compute buf0; write kt+1 (slot B) -> buf1; load kt+2 -> slot A
        if (kt + 1 <= KB2) STG_WRITE(1, kb0, kb1, vb0, vb1);
        if (kt + 2 <= KB2) STG_LOAD(kt + 2, ka0, ka1, va0, va1);
        attn_step(kt, kmaxw, qrow, lo, hi, Ks[0], Vs[0], Pw, aq, o_acc, m_i, l_i);
        __syncthreads();
        ++kt;
        if (kt > KB2) break;
        // odd step: compute buf1; write kt+1 (slot A) -> buf0; load kt+2 -> slot B
        if (kt + 1 <= KB2) STG_WRITE(0, ka0, ka1, va0, va1);
        if (kt + 2 <= KB2) STG_LOAD(kt + 2, kb0, kb1, vb0, vb1);
        attn_step(kt, kmaxw, qrow, lo, hi, Ks[1], Vs[1], Pw, aq, o_acc, m_i, l_i);
        __syncthreads();
        ++kt;
    }

    #pragma unroll
    for (int m = 0; m < 2; ++m)
        #pragma unroll
        for (int t = 0; t < 4; ++t)
            #pragma unroll
            for (int r = 0; r < 4; ++r) {
                float v = o_acc[m][t][r] / l_i[m][r];
                O[(rowQ + qrow + m * 16 + hi * 4 + r) * 512 + colBase + t * 16 + lo] = f2bf(v);
            }
}

extern "C" void kernel_launch(void* const* d_in, const int* in_sizes, int n_in,
                              void* d_out, int out_size, void* d_ws, size_t ws_size,
                              hipStream_t stream)
{
    (void)in_sizes; (void)n_in; (void)out_size; (void)ws_size;
    const float* x   = (const float*)d_in[0];
    const float* w_q = (const float*)d_in[1];
    const float* w_k = (const float*)d_in[2];
    const float* w_v = (const float*)d_in[3];
    const float* ipw = (const float*)d_in[4];
    const float* ipb = (const float*)d_in[5];
    const float* ow  = (const float*)d_in[6];
    const float* ob  = (const float*)d_in[7];

    const int M = 16384, D = 512;
    const size_t SZ = (size_t)M * D;        // 8,388,608 elems
    // Workspace layout (104.5 MB total, < proven 117 MB envelope):
    //   xb: [SZ]      x in bf16; dead after stage 1 -> reused as Qb
    //   weights: 1.84M elems bf16
    //   T:  [3*SZ]    rope'd projections; dead after stage 3 -> T[0..SZ) reused as Cb
    //   Kb: [SZ], Vt: [SZ]
    unsigned short* xb   = (unsigned short*)d_ws;
    unsigned short* wqb  = xb + SZ;
    unsigned short* wkb  = wqb + 262144;
    unsigned short* wvb  = wkb + 262144;
    unsigned short* ipwb = wvb + 262144;
    unsigned short* owb  = ipwb + 786432;
    unsigned short* T    = owb + 262144;     // 3 x [M,D]
    unsigned short* Kb   = T + 3 * SZ;
    unsigned short* Vt   = Kb + SZ;          // [64 bh][64 d][2048 m]
    unsigned short* Qb   = xb;               // reuse xb after stage 1
    unsigned short* Cb   = T;                // reuse T after stage 3

    dim3 blk(256);
    dim3 gg(D / 128, M / 128);               // (4, 128)

    // Stage 0: convert inputs to bf16
    cvt_one<<<dim3((int)(SZ / 8 / 256)), blk, 0, stream>>>(x, xb, (int)(SZ / 8));
    cvt_one<<<dim3(128), blk, 0, stream>>>(w_q, wqb, 32768);
    cvt_one<<<dim3(128), blk, 0, stream>>>(w_k, wkb, 32768);
    cvt_one<<<dim3(128), blk, 0, stream>>>(w_v, wvb, 32768);
    cvt_one<<<dim3(384), blk, 0, stream>>>(ipw, ipwb, 98304);
    cvt_one<<<dim3(128), blk, 0, stream>>>(ow, owb, 32768);

    // Stage 1: T = x @ w^T
    gemm_bt<0, 0><<<gg, blk, 0, stream>>>(xb, wqb, nullptr, T,          M, D, D);
    gemm_bt<0, 0><<<gg, blk, 0, stream>>>(xb, wkb, nullptr, T + SZ,     M, D, D);
    gemm_bt<0, 0><<<gg, blk, 0, stream>>>(xb, wvb, nullptr, T + 2 * SZ, M, D, D);

    // Stage 2: RoPE in-place
    rope_kernel<<<dim3(3 * M * 64 / 256), blk, 0, stream>>>(T);

    // Stage 3: in_proj with bias (V written transposed; Q overwrites xb)
    gemm_bt<1, 0><<<gg, blk, 0, stream>>>(T,          ipwb,          ipb,        Qb, M, D, D);
    gemm_bt<1, 0><<<gg, blk, 0, stream>>>(T + SZ,     ipwb + 262144, ipb + 512,  Kb, M, D, D);
    gemm_bt<1, 2><<<gg, blk, 0, stream>>>(T + 2 * SZ, ipwb + 524288, ipb + 1024, Vt, M, D, D);

    // Stage 4: causal flash attention (paired q-tiles for load balance; writes into T)
    attn_kernel<<<dim3(16, 64), blk, 0, stream>>>(Qb, Kb, Vt, Cb);

    // Stage 5: output projection (f32 out)
    gemm_bt<1, 1><<<gg, blk, 0, stream>>>(Cb, owb, ob, (float*)d_out, M, D, D);
}

// Round 8
// 357.493 us; speedup vs baseline: 2.0342x; 1.2323x over previous
//
#include <hip/hip_runtime.h>
#include <hip/hip_bf16.h>

typedef __attribute__((ext_vector_type(8))) short short8;
typedef __attribute__((ext_vector_type(4))) short short4v;
typedef __attribute__((ext_vector_type(4))) float f32x4;

__device__ __forceinline__ float bf2f(unsigned short u) {
    union { unsigned int i; float f; } v; v.i = ((unsigned int)u) << 16; return v.f;
}
__device__ __forceinline__ unsigned short f2bf(float f) {
    union { float f; unsigned int i; } v; v.f = f;
    unsigned int r = v.i + 0x7fffu + ((v.i >> 16) & 1u);
    return (unsigned short)(r >> 16);
}

#define GLDS16(g, l) __builtin_amdgcn_global_load_lds( \
    (const __attribute__((address_space(1))) unsigned int*)(g), \
    (__attribute__((address_space(3))) unsigned int*)(l), 16, 0, 0)

// ---------------- f32 -> bf16 conversion (vectorized) ----------------
__global__ __launch_bounds__(256) void cvt_one(
    const float* __restrict__ in, unsigned short* __restrict__ out, int nchunk)
{
    int i = blockIdx.x * 256 + threadIdx.x;
    if (i >= nchunk) return;
    f32x4 a = *(const f32x4*)&in[(size_t)i * 8];
    f32x4 b = *(const f32x4*)&in[(size_t)i * 8 + 4];
    short8 o;
    o[0] = (short)f2bf(a[0]); o[1] = (short)f2bf(a[1]);
    o[2] = (short)f2bf(a[2]); o[3] = (short)f2bf(a[3]);
    o[4] = (short)f2bf(b[0]); o[5] = (short)f2bf(b[1]);
    o[6] = (short)f2bf(b[2]); o[7] = (short)f2bf(b[3]);
    *(short8*)&out[(size_t)i * 8] = o;
}

// ---------------- bf16 GEMM, m97 structure ----------------
// C[M,N] = A[M,K] @ B[N,K]^T (+bias). A,B bf16 row-major.
// OUT: 0 = bf16 row-major, 1 = f32 row-major, 2 = bf16 transposed-V layout
template<int HAS_BIAS, int OUT>
__global__ __launch_bounds__(256) void gemm_bt(
    const unsigned short* __restrict__ A, const unsigned short* __restrict__ B,
    const float* __restrict__ bias, void* __restrict__ Cp,
    int M, int N, int K)
{
    __shared__ __align__(16) short As[128 * 64];
    __shared__ __align__(16) short Bs[128 * 64];
    const int tid  = threadIdx.x;
    const int lane = tid & 63;
    const int wave = tid >> 6;
    const int wr = wave >> 1, wc = wave & 1;
    const int lo = lane & 15, hi = lane >> 4;
    const int rowBase = blockIdx.y * 128;
    const int colBase = blockIdx.x * 128;

    f32x4 acc[4][4] = {};

    for (int k0 = 0; k0 < K; k0 += 64) {
        const unsigned short* Ab = A + (size_t)rowBase * K + k0;
        const unsigned short* Bb = B + (size_t)colBase * K + k0;
        #pragma unroll
        for (int p = 0; p < 4; ++p) {
            int o = p * 256 + tid;
            GLDS16(&Ab[(size_t)(o >> 3) * K + (o & 7) * 8], &As[o * 8]);
        }
        #pragma unroll
        for (int p = 0; p < 4; ++p) {
            int o = p * 256 + tid;
            GLDS16(&Bb[(size_t)(o >> 3) * K + (o & 7) * 8], &Bs[o * 8]);
        }
        __syncthreads();
        #pragma unroll
        for (int s = 0; s < 2; ++s) {
            short8 a[4], b[4];
            #pragma unroll
            for (int i = 0; i < 4; ++i)
                a[i] = *(const short8*)&As[(wr * 64 + i * 16 + lo) * 64 + s * 32 + hi * 8];
            #pragma unroll
            for (int j = 0; j < 4; ++j)
                b[j] = *(const short8*)&Bs[(wc * 64 + j * 16 + lo) * 64 + s * 32 + hi * 8];
            #pragma unroll
            for (int i = 0; i < 4; ++i)
                #pragma unroll
                for (int j = 0; j < 4; ++j)
                    acc[i][j] = __builtin_amdgcn_mfma_f32_16x16x32_bf16(a[i], b[j], acc[i][j], 0, 0, 0);
        }
        __syncthreads();
    }

    #pragma unroll
    for (int i = 0; i < 4; ++i) {
        int rowA = rowBase + wr * 64 + i * 16 + hi * 4;
        #pragma unroll
        for (int j = 0; j < 4; ++j) {
            int col = colBase + wc * 64 + j * 16 + lo;
            float bv = HAS_BIAS ? bias[col] : 0.0f;
            if (OUT == 2) {
                short4v sv;
                #pragma unroll
                for (int r = 0; r < 4; ++r) sv[r] = (short)f2bf(acc[i][j][r] + bv);
                size_t idx = (((size_t)(rowA >> 11) * 8 + (col >> 6)) * 64 + (col & 63)) * 2048
                             + (rowA & 2047);
                *(short4v*)&((unsigned short*)Cp)[idx] = sv;
            } else {
                #pragma unroll
                for (int r = 0; r < 4; ++r) {
                    float v = acc[i][j][r] + bv;
                    if (OUT == 1) ((float*)Cp)[(size_t)(rowA + r) * N + col] = v;
                    else          ((unsigned short*)Cp)[(size_t)(rowA + r) * N + col] = f2bf(v);
                }
            }
        }
    }
}

// ---------------- RoPE in-place, rows of [*, 512] bf16, pos = row % 2048 ----------------
__global__ __launch_bounds__(256) void rope_kernel(unsigned short* __restrict__ T)
{
    int gid = blockIdx.x * 256 + threadIdx.x;
    int row = gid >> 6;
    int seg = (gid & 63) * 8;
    int pos = row & 2047;
    short8 v = *(short8*)&T[(size_t)row * 512 + seg];
    const float THC = -0.05190512648261308f;  // -2*log2(10000)/512
    #pragma unroll
    for (int p = 0; p < 4; ++p) {
        int i = (seg >> 1) + p;
        float theta = exp2f(THC * ((float)i - 1.0f));
        float ang = (float)pos * theta;
        float sn, cs;
        sincosf(ang, &sn, &cs);
        float e = bf2f((unsigned short)v[2 * p]);
        float o = bf2f((unsigned short)v[2 * p + 1]);
        v[2 * p]     = (short)f2bf(e * cs + o * sn);
        v[2 * p + 1] = (short)f2bf(-e * sn + o * cs);
    }
    *(short8*)&T[(size_t)row * 512 + seg] = v;
}

// ---------------- causal flash attention ----------------
// Q/K/O: [16384, 512] bf16; Vt: [64 bh][64 d][2048 m] bf16.
// Grid (64 bh, 32 y), qb = 31-y (longest blocks first -> LPT balance).
// Block = one 64-row q-tile; 4 waves x 16 rows, all waves active every iter.
// K/V double-buffered in LDS, XOR-swizzled (T2), loads issued 2 tiles ahead.
// Same-bh blocks share an XCD (linear id mod 8 == bh mod 8) for L2 reuse of K/V.

__device__ __forceinline__ void attn_step(
    int kt, int NT, int qrow, int lo, int hi,
    const short* __restrict__ KsB, const short* __restrict__ VsB,
    short* __restrict__ Pw,
    short8 (&aq)[2], f32x4 (&o_acc)[4],
    float (&m_i)[4], float (&l_i)[4])
{
    const int swz = (lo & 7) << 3;

    f32x4 sa[4] = {};
    #pragma unroll
    for (int s = 0; s < 2; ++s) {
        short8 bk[4];
        #pragma unroll
        for (int n = 0; n < 4; ++n)
            bk[n] = *(const short8*)&KsB[(n * 16 + lo) * 64 + ((s * 32 + hi * 8) ^ swz)];
        #pragma unroll
        for (int n = 0; n < 4; ++n)
            sa[n] = __builtin_amdgcn_mfma_f32_16x16x32_bf16(aq[s], bk[n], sa[n], 0, 0, 0);
    }

    const bool need_mask = (kt == NT - 1);
    float sv[4][4];
    #pragma unroll
    for (int n = 0; n < 4; ++n) {
        int key = kt * 64 + n * 16 + lo;
        #pragma unroll
        for (int r = 0; r < 4; ++r) {
            float x = sa[n][r] * 0.125f;
            if (need_mask) {
                int qr = qrow + hi * 4 + r;
                if (key > qr) x = -1e30f;
            }
            sv[n][r] = x;
        }
    }

    float alpha[4];
    #pragma unroll
    for (int r = 0; r < 4; ++r) {
        float x = fmaxf(fmaxf(sv[0][r], sv[1][r]), fmaxf(sv[2][r], sv[3][r]));
        #pragma unroll
        for (int off = 1; off < 16; off <<= 1) x = fmaxf(x, __shfl_xor(x, off));
        float mn = fmaxf(m_i[r], x);
        alpha[r] = __expf(m_i[r] - mn);
        m_i[r] = mn;
    }
    #pragma unroll
    for (int n = 0; n < 4; ++n)
        #pragma unroll
        for (int r = 0; r < 4; ++r)
            sv[n][r] = __expf(sv[n][r] - m_i[r]);

    #pragma unroll
    for (int r = 0; r < 4; ++r) {
        float x = sv[0][r] + sv[1][r] + sv[2][r] + sv[3][r];
        #pragma unroll
        for (int off = 1; off < 16; off <<= 1) x += __shfl_xor(x, off);
        l_i[r] = l_i[r] * alpha[r] + x;
    }
    #pragma unroll
    for (int t = 0; t < 4; ++t)
        #pragma unroll
        for (int r = 0; r < 4; ++r)
            o_acc[t][r] *= alpha[r];

    #pragma unroll
    for (int n = 0; n < 4; ++n)
        #pragma unroll
        for (int r = 0; r < 4; ++r)
            Pw[(hi * 4 + r) * 72 + n * 16 + lo] = (short)f2bf(sv[n][r]);

    #pragma unroll
    for (int s = 0; s < 2; ++s) {
        short8 ap = *(const short8*)&Pw[lo * 72 + s * 32 + hi * 8];
        #pragma unroll
        for (int t = 0; t < 4; ++t) {
            short8 bv = *(const short8*)&VsB[(t * 16 + lo) * 64 + ((s * 32 + hi * 8) ^ swz)];
            o_acc[t] = __builtin_amdgcn_mfma_f32_16x16x32_bf16(ap, bv, o_acc[t], 0, 0, 0);
        }
    }
}

#define STG_LOAD(kt, KR0, KR1, VR0, VR1) { \
    int rr = tid >> 3, cc = (tid & 7) * 8; \
    KR0 = *(const short8*)&Kp[(rowQ + (size_t)((kt) * 64 + rr)) * 512 + colBase + cc]; \
    KR1 = *(const short8*)&Kp[(rowQ + (size_t)((kt) * 64 + rr + 32)) * 512 + colBase + cc]; \
    VR0 = *(const short8*)&Vh[(size_t)rr * 2048 + (kt) * 64 + cc]; \
    VR1 = *(const short8*)&Vh[(size_t)(rr + 32) * 2048 + (kt) * 64 + cc]; }

// XOR-swizzled LDS write: short idx = row*64 + (slot*8 ^ ((row&7)<<3));
// (rr and rr+32 share rr&7, so one swizzle serves both rows)
#define STG_WRITE(BUF, KR0, KR1, VR0, VR1) { \
    int rr = tid >> 3; \
    int sw = ((tid & 7) * 8) ^ ((rr & 7) << 3); \
    *(short8*)&Ks[BUF][rr * 64 + sw] = KR0; \
    *(short8*)&Ks[BUF][(rr + 32) * 64 + sw] = KR1; \
    *(short8*)&Vs[BUF][rr * 64 + sw] = VR0; \
    *(short8*)&Vs[BUF][(rr + 32) * 64 + sw] = VR1; }

__global__ __launch_bounds__(256, 3) void attn_kernel(
    const unsigned short* __restrict__ Q, const unsigned short* __restrict__ Kp,
    const unsigned short* __restrict__ Vt, unsigned short* __restrict__ O)
{
    const int tid = threadIdx.x, lane = tid & 63, wave = tid >> 6;
    const int lo = lane & 15, hi = lane >> 4;
    const int bh = blockIdx.x;
    const int qb = 31 - blockIdx.y;         // longest q-tiles dispatch first (LPT)
    const int bb = bh >> 3, hh = bh & 7;
    const int NT = qb + 1;

    __shared__ __align__(16) short Ks[2][64 * 64];
    __shared__ __align__(16) short Vs[2][64 * 64];
    __shared__ __align__(16) short P[4][16 * 72];
    short* Pw = P[wave];

    const size_t rowQ = (size_t)bb * 2048;
    const int colBase = hh * 64;
    const unsigned short* Vh = Vt + (size_t)bh * 64 * 2048;
    const int qrow = qb * 64 + wave * 16;

    short8 aq[2];
    #pragma unroll
    for (int s = 0; s < 2; ++s)
        aq[s] = *(const short8*)&Q[(rowQ + qrow + lo) * 512 + colBase + s * 32 + hi * 8];

    f32x4 o_acc[4] = {};
    float m_i[4], l_i[4];
    #pragma unroll
    for (int r = 0; r < 4; ++r) { m_i[r] = -1e30f; l_i[r] = 0.0f; }

    short8 ka0, ka1, va0, va1;   // slot A (even kt data)
    short8 kb0, kb1, vb0, vb1;   // slot B (odd kt data)

    STG_LOAD(0, ka0, ka1, va0, va1);
    STG_WRITE(0, ka0, ka1, va0, va1);
    if (1 < NT) STG_LOAD(1, kb0, kb1, vb0, vb1);
    __syncthreads();

    for (int kt = 0; kt < NT; ) {
        // even step: compute buf0; write kt+1 (slot B) -> buf1; load kt+2 -> slot A
        if (kt + 1 < NT) STG_WRITE(1, kb0, kb1, vb0, vb1);
        if (kt + 2 < NT) STG_LOAD(kt + 2, ka0, ka1, va0, va1);
        attn_step(kt, NT, qrow, lo, hi, Ks[0], Vs[0], Pw, aq, o_acc, m_i, l_i);
        __syncthreads();
        ++kt;
        if (kt >= NT) break;
        // odd step: compute buf1; write kt+1 (slot A) -> buf0; load kt+2 -> slot B
        if (kt + 1 < NT) STG_WRITE(0, ka0, ka1, va0, va1);
        if (kt + 2 < NT) STG_LOAD(kt + 2, kb0, kb1, vb0, vb1);
        attn_step(kt, NT, qrow, lo, hi, Ks[1], Vs[1], Pw, aq, o_acc, m_i, l_i);
        __syncthreads();
        ++kt;
    }

    #pragma unroll
    for (int t = 0; t < 4; ++t)
        #pragma unroll
        for (int r = 0; r < 4; ++r) {
            float v = o_acc[t][r] / l_i[r];
            O[(rowQ + qrow + hi * 4 + r) * 512 + colBase + t * 16 + lo] = f2bf(v);
        }
}

extern "C" void kernel_launch(void* const* d_in, const int* in_sizes, int n_in,
                              void* d_out, int out_size, void* d_ws, size_t ws_size,
                              hipStream_t stream)
{
    (void)in_sizes; (void)n_in; (void)out_size; (void)ws_size;
    const float* x   = (const float*)d_in[0];
    const float* w_q = (const float*)d_in[1];
    const float* w_k = (const float*)d_in[2];
    const float* w_v = (const float*)d_in[3];
    const float* ipw = (const float*)d_in[4];
    const float* ipb = (const float*)d_in[5];
    const float* ow  = (const float*)d_in[6];
    const float* ob  = (const float*)d_in[7];

    const int M = 16384, D = 512;
    const size_t SZ = (size_t)M * D;        // 8,388,608 elems
    // Workspace layout (104.5 MB total):
    //   xb: [SZ]      x in bf16; dead after stage 1 -> reused as Qb
    //   weights: 1.84M elems bf16
    //   T:  [3*SZ]    rope'd projections; dead after stage 3 -> T[0..SZ) reused as Cb
    //   Kb: [SZ], Vt: [SZ]
    unsigned short* xb   = (unsigned short*)d_ws;
    unsigned short* wqb  = xb + SZ;
    unsigned short* wkb  = wqb + 262144;
    unsigned short* wvb  = wkb + 262144;
    unsigned short* ipwb = wvb + 262144;
    unsigned short* owb  = ipwb + 786432;
    unsigned short* T    = owb + 262144;     // 3 x [M,D]
    unsigned short* Kb   = T + 3 * SZ;
    unsigned short* Vt   = Kb + SZ;          // [64 bh][64 d][2048 m]
    unsigned short* Qb   = xb;               // reuse xb after stage 1
    unsigned short* Cb   = T;                // reuse T after stage 3

    dim3 blk(256);
    dim3 gg(D / 128, M / 128);               // (4, 128)

    // Stage 0: convert inputs to bf16
    cvt_one<<<dim3((int)(SZ / 8 / 256)), blk, 0, stream>>>(x, xb, (int)(SZ / 8));
    cvt_one<<<dim3(128), blk, 0, stream>>>(w_q, wqb, 32768);
    cvt_one<<<dim3(128), blk, 0, stream>>>(w_k, wkb, 32768);
    cvt_one<<<dim3(128), blk, 0, stream>>>(w_v, wvb, 32768);
    cvt_one<<<dim3(384), blk, 0, stream>>>(ipw, ipwb, 98304);
    cvt_one<<<dim3(128), blk, 0, stream>>>(ow, owb, 32768);

    // Stage 1: T = x @ w^T
    gemm_bt<0, 0><<<gg, blk, 0, stream>>>(xb, wqb, nullptr, T,          M, D, D);
    gemm_bt<0, 0><<<gg, blk, 0, stream>>>(xb, wkb, nullptr, T + SZ,     M, D, D);
    gemm_bt<0, 0><<<gg, blk, 0, stream>>>(xb, wvb, nullptr, T + 2 * SZ, M, D, D);

    // Stage 2: RoPE in-place
    rope_kernel<<<dim3(3 * M * 64 / 256), blk, 0, stream>>>(T);

    // Stage 3: in_proj with bias (V written transposed; Q overwrites xb)
    gemm_bt<1, 0><<<gg, blk, 0, stream>>>(T,          ipwb,          ipb,        Qb, M, D, D);
    gemm_bt<1, 0><<<gg, blk, 0, stream>>>(T + SZ,     ipwb + 262144, ipb + 512,  Kb, M, D, D);
    gemm_bt<1, 2><<<gg, blk, 0, stream>>>(T + 2 * SZ, ipwb + 524288, ipb + 1024, Vt, M, D, D);

    // Stage 4: causal flash attention (LPT-ordered, XCD-local per bh)
    attn_kernel<<<dim3(64, 32), blk, 0, stream>>>(Qb, Kb, Vt, Cb);

    // Stage 5: output projection (f32 out)
    gemm_bt<1, 1><<<gg, blk, 0, stream>>>(Cb, owb, ob, (float*)d_out, M, D, D);
}

// Round 9
// 338.728 us; speedup vs baseline: 2.1469x; 1.0554x over previous
//
#include <hip/hip_runtime.h>
#include <hip/hip_bf16.h>

typedef __attribute__((ext_vector_type(8))) short short8;
typedef __attribute__((ext_vector_type(4))) short short4v;
typedef __attribute__((ext_vector_type(4))) float f32x4;

__device__ __forceinline__ float bf2f(unsigned short u) {
    union { unsigned int i; float f; } v; v.i = ((unsigned int)u) << 16; return v.f;
}
// native HW conversion (compiler emits v_cvt_pk_bf16_f32 for pairs)
__device__ __forceinline__ unsigned short f2bfh(float f) {
    union { __hip_bfloat16 h; unsigned short u; } c;
    c.h = __float2bfloat16(f);
    return c.u;
}

#define GLDS16(g, l) __builtin_amdgcn_global_load_lds( \
    (const __attribute__((address_space(1))) unsigned int*)(g), \
    (__attribute__((address_space(3))) unsigned int*)(l), 16, 0, 0)

// ---------------- f32 -> bf16 conversion kernels ----------------
__global__ __launch_bounds__(256) void cvt_one(
    const float* __restrict__ in, unsigned short* __restrict__ out, int nchunk)
{
    int i = blockIdx.x * 256 + threadIdx.x;
    if (i >= nchunk) return;
    f32x4 a = *(const f32x4*)&in[(size_t)i * 8];
    f32x4 b = *(const f32x4*)&in[(size_t)i * 8 + 4];
    short8 o;
    o[0] = (short)f2bfh(a[0]); o[1] = (short)f2bfh(a[1]);
    o[2] = (short)f2bfh(a[2]); o[3] = (short)f2bfh(a[3]);
    o[4] = (short)f2bfh(b[0]); o[5] = (short)f2bfh(b[1]);
    o[6] = (short)f2bfh(b[2]); o[7] = (short)f2bfh(b[3]);
    *(short8*)&out[(size_t)i * 8] = o;
}

// all 7 weight matrices (each 512x512, 32768 chunks of 8) in one launch; grid (128, 7)
__global__ __launch_bounds__(256) void cvt_w(
    const float* __restrict__ wq, const float* __restrict__ wk, const float* __restrict__ wv,
    const float* __restrict__ ipw, const float* __restrict__ ow,
    unsigned short* __restrict__ wqb, unsigned short* __restrict__ ipwb,
    unsigned short* __restrict__ owb)
{
    int z = blockIdx.y;
    const float* src;
    unsigned short* dst;
    if (z < 3)      { src = (z == 0 ? wq : z == 1 ? wk : wv); dst = wqb + (size_t)z * 262144; }
    else if (z < 6) { src = ipw + (size_t)(z - 3) * 262144;   dst = ipwb + (size_t)(z - 3) * 262144; }
    else            { src = ow;                                dst = owb; }
    int i = blockIdx.x * 256 + threadIdx.x;  // 0..32767
    f32x4 a = *(const f32x4*)&src[(size_t)i * 8];
    f32x4 b = *(const f32x4*)&src[(size_t)i * 8 + 4];
    short8 o;
    o[0] = (short)f2bfh(a[0]); o[1] = (short)f2bfh(a[1]);
    o[2] = (short)f2bfh(a[2]); o[3] = (short)f2bfh(a[3]);
    o[4] = (short)f2bfh(b[0]); o[5] = (short)f2bfh(b[1]);
    o[6] = (short)f2bfh(b[2]); o[7] = (short)f2bfh(b[3]);
    *(short8*)&dst[(size_t)i * 8] = o;
}

// ---------------- RoPE cos/sin table: [2048 pos][256 i] ----------------
__global__ __launch_bounds__(256) void rope_table(float* __restrict__ ct, float* __restrict__ st)
{
    int i = threadIdx.x;      // 0..255
    int pos = blockIdx.x;     // 0..2047
    const float THC = -0.05190512648261308f;  // -2*log2(10000)/512
    float theta = exp2f(THC * ((float)i - 1.0f));
    float ang = (float)pos * theta;
    float sn, cs;
    sincosf(ang, &sn, &cs);
    ct[pos * 256 + i] = cs;
    st[pos * 256 + i] = sn;
}

// ---------------- shared GEMM core (128x128 tile, BK=64, global_load_lds) ----------------
__device__ __forceinline__ void gemm_core(
    const unsigned short* __restrict__ A, int lda,
    const unsigned short* __restrict__ B, int K,
    int rowBase, int colBase, int tid, int lane, int wave,
    short* As, short* Bs, f32x4 (&acc)[4][4])
{
    const int wr = wave >> 1, wc = wave & 1;
    const int lo = lane & 15, hi = lane >> 4;
    for (int k0 = 0; k0 < K; k0 += 64) {
        const unsigned short* Ab = A + (size_t)rowBase * lda + k0;
        const unsigned short* Bb = B + (size_t)colBase * K + k0;
        #pragma unroll
        for (int p = 0; p < 4; ++p) {
            int o = p * 256 + tid;
            GLDS16(&Ab[(size_t)(o >> 3) * lda + (o & 7) * 8], &As[o * 8]);
        }
        #pragma unroll
        for (int p = 0; p < 4; ++p) {
            int o = p * 256 + tid;
            GLDS16(&Bb[(size_t)(o >> 3) * K + (o & 7) * 8], &Bs[o * 8]);
        }
        __syncthreads();
        #pragma unroll
        for (int s = 0; s < 2; ++s) {
            short8 a[4], b[4];
            #pragma unroll
            for (int i = 0; i < 4; ++i)
                a[i] = *(const short8*)&As[(wr * 64 + i * 16 + lo) * 64 + s * 32 + hi * 8];
            #pragma unroll
            for (int j = 0; j < 4; ++j)
                b[j] = *(const short8*)&Bs[(wc * 64 + j * 16 + lo) * 64 + s * 32 + hi * 8];
            #pragma unroll
            for (int i = 0; i < 4; ++i)
                #pragma unroll
                for (int j = 0; j < 4; ++j)
                    acc[i][j] = __builtin_amdgcn_mfma_f32_16x16x32_bf16(a[i], b[j], acc[i][j], 0, 0, 0);
        }
        __syncthreads();
    }
}

// C[M,N] = A[M,K] @ B[N,K]^T (+bias). OUT: 0 = bf16 row-major, 1 = f32 row-major.
template<int HAS_BIAS, int OUT>
__global__ __launch_bounds__(256) void gemm_bt(
    const unsigned short* __restrict__ A, int lda, const unsigned short* __restrict__ B,
    const float* __restrict__ bias, void* __restrict__ Cp,
    int M, int N, int K)
{
    __shared__ __align__(16) short As[128 * 64];
    __shared__ __align__(16) short Bs[128 * 64];
    const int tid = threadIdx.x, lane = tid & 63, wave = tid >> 6;
    const int wr = wave >> 1, wc = wave & 1;
    const int lo = lane & 15, hi = lane >> 4;
    const int rowBase = blockIdx.y * 128;
    const int colBase = blockIdx.x * 128;

    f32x4 acc[4][4] = {};
    gemm_core(A, lda, B, K, rowBase, colBase, tid, lane, wave, As, Bs, acc);

    #pragma unroll
    for (int i = 0; i < 4; ++i) {
        int rowA = rowBase + wr * 64 + i * 16 + hi * 4;
        #pragma unroll
        for (int j = 0; j < 4; ++j) {
            int col = colBase + wc * 64 + j * 16 + lo;
            float bv = HAS_BIAS ? bias[col] : 0.0f;
            #pragma unroll
            for (int r = 0; r < 4; ++r) {
                float v = acc[i][j][r] + bv;
                if (OUT == 1) ((float*)Cp)[(size_t)(rowA + r) * N + col] = v;
                else          ((unsigned short*)Cp)[(size_t)(rowA + r) * N + col] = f2bfh(v);
            }
        }
    }
}

// Stage-3 grouped in_proj: z=0 -> Qb, z=1 -> Kb (row-major), z=2 -> Vt (transposed layout).
// A = T[:, z*512 : z*512+512] with lda=1536.
__global__ __launch_bounds__(256) void gemm_inproj(
    const unsigned short* __restrict__ T, const unsigned short* __restrict__ ipwb,
    const float* __restrict__ ipb,
    unsigned short* __restrict__ Qb, unsigned short* __restrict__ Kb,
    unsigned short* __restrict__ Vt)
{
    __shared__ __align__(16) short As[128 * 64];
    __shared__ __align__(16) short Bs[128 * 64];
    const int tid = threadIdx.x, lane = tid & 63, wave = tid >> 6;
    const int wr = wave >> 1, wc = wave & 1;
    const int lo = lane & 15, hi = lane >> 4;
    const int rowBase = blockIdx.y * 128;
    const int colBase = blockIdx.x * 128;
    const int z = blockIdx.z;

    const unsigned short* A = T + z * 512;
    const unsigned short* B = ipwb + (size_t)z * 262144;
    const float* bias = ipb + z * 512;

    f32x4 acc[4][4] = {};
    gemm_core(A, 1536, B, 512, rowBase, colBase, tid, lane, wave, As, Bs, acc);

    unsigned short* Crm = (z == 0) ? Qb : Kb;
    #pragma unroll
    for (int i = 0; i < 4; ++i) {
        int rowA = rowBase + wr * 64 + i * 16 + hi * 4;
        #pragma unroll
        for (int j = 0; j < 4; ++j) {
            int col = colBase + wc * 64 + j * 16 + lo;
            float bv = bias[col];
            if (z == 2) {
                short4v sv;
                #pragma unroll
                for (int r = 0; r < 4; ++r) sv[r] = (short)f2bfh(acc[i][j][r] + bv);
                size_t idx = (((size_t)(rowA >> 11) * 8 + (col >> 6)) * 64 + (col & 63)) * 2048
                             + (rowA & 2047);
                *(short4v*)&Vt[idx] = sv;
            } else {
                #pragma unroll
                for (int r = 0; r < 4; ++r)
                    Crm[(size_t)(rowA + r) * 512 + col] = f2bfh(acc[i][j][r] + bv);
            }
        }
    }
}

// ---------------- RoPE in-place over T[16384, 1536], table-driven ----------------
__global__ __launch_bounds__(192) void rope_kernel(
    unsigned short* __restrict__ T,
    const float* __restrict__ ct, const float* __restrict__ st)
{
    int row = blockIdx.x;          // 0..16383
    int c0 = threadIdx.x * 8;      // 0..1528
    int pos = row & 2047;
    int i0 = (c0 & 511) >> 1;      // multiple of 4
    short8 v = *(short8*)&T[(size_t)row * 1536 + c0];
    f32x4 cs = *(const f32x4*)&ct[pos * 256 + i0];
    f32x4 sn = *(const f32x4*)&st[pos * 256 + i0];
    #pragma unroll
    for (int p = 0; p < 4; ++p) {
        float e = bf2f((unsigned short)v[2 * p]);
        float o = bf2f((unsigned short)v[2 * p + 1]);
        v[2 * p]     = (short)f2bfh(e * cs[p] + o * sn[p]);
        v[2 * p + 1] = (short)f2bfh(-e * sn[p] + o * cs[p]);
    }
    *(short8*)&T[(size_t)row * 1536 + c0] = v;
}

// ---------------- causal flash attention ----------------
// Q/K/O: [16384, 512] bf16; Vt: [64 bh][64 d][2048 m] bf16.
// Grid (64 bh, 32 y), qb = 31-y (LPT). Block = one 64-row q-tile, 4 waves x 16 rows.
// K/V double-buffered in LDS, XOR-swizzled, loads 2 tiles ahead. Q pre-scaled by 0.125.

__device__ __forceinline__ void attn_step(
    int kt, int NT, int qrow, int lo, int hi,
    const short* __restrict__ KsB, const short* __restrict__ VsB,
    short* __restrict__ Pw,
    short8 (&aq)[2], f32x4 (&o_acc)[4],
    float (&m_i)[4], float (&l_i)[4])
{
    const int swz = (lo & 7) << 3;

    f32x4 sa[4] = {};
    #pragma unroll
    for (int s = 0; s < 2; ++s) {
        short8 bk[4];
        #pragma unroll
        for (int n = 0; n < 4; ++n)
            bk[n] = *(const short8*)&KsB[(n * 16 + lo) * 64 + ((s * 32 + hi * 8) ^ swz)];
        #pragma unroll
        for (int n = 0; n < 4; ++n)
            sa[n] = __builtin_amdgcn_mfma_f32_16x16x32_bf16(aq[s], bk[n], sa[n], 0, 0, 0);
    }

    const bool need_mask = (kt == NT - 1);
    float sv[4][4];
    #pragma unroll
    for (int n = 0; n < 4; ++n) {
        int key = kt * 64 + n * 16 + lo;
        #pragma unroll
        for (int r = 0; r < 4; ++r) {
            float x = sa[n][r];
            if (need_mask) {
                int qr = qrow + hi * 4 + r;
                if (key > qr) x = -1e30f;
            }
            sv[n][r] = x;
        }
    }

    float alpha[4];
    #pragma unroll
    for (int r = 0; r < 4; ++r) {
        float x = fmaxf(fmaxf(sv[0][r], sv[1][r]), fmaxf(sv[2][r], sv[3][r]));
        #pragma unroll
        for (int off = 1; off < 16; off <<= 1) x = fmaxf(x, __shfl_xor(x, off));
        float mn = fmaxf(m_i[r], x);
        alpha[r] = __expf(m_i[r] - mn);
        m_i[r] = mn;
    }
    #pragma unroll
    for (int n = 0; n < 4; ++n)
        #pragma unroll
        for (int r = 0; r < 4; ++r)
            sv[n][r] = __expf(sv[n][r] - m_i[r]);

    #pragma unroll
    for (int r = 0; r < 4; ++r) {
        float x = sv[0][r] + sv[1][r] + sv[2][r] + sv[3][r];
        #pragma unroll
        for (int off = 1; off < 16; off <<= 1) x += __shfl_xor(x, off);
        l_i[r] = l_i[r] * alpha[r] + x;
    }
    #pragma unroll
    for (int t = 0; t < 4; ++t)
        #pragma unroll
        for (int r = 0; r < 4; ++r)
            o_acc[t][r] *= alpha[r];

    #pragma unroll
    for (int n = 0; n < 4; ++n)
        #pragma unroll
        for (int r = 0; r < 4; ++r)
            Pw[(hi * 4 + r) * 72 + n * 16 + lo] = (short)f2bfh(sv[n][r]);

    #pragma unroll
    for (int s = 0; s < 2; ++s) {
        short8 ap = *(const short8*)&Pw[lo * 72 + s * 32 + hi * 8];
        #pragma unroll
        for (int t = 0; t < 4; ++t) {
            short8 bv = *(const short8*)&VsB[(t * 16 + lo) * 64 + ((s * 32 + hi * 8) ^ swz)];
            o_acc[t] = __builtin_amdgcn_mfma_f32_16x16x32_bf16(ap, bv, o_acc[t], 0, 0, 0);
        }
    }
}

#define STG_LOAD(kt, KR0, KR1, VR0, VR1) { \
    int rr = tid >> 3, cc = (tid & 7) * 8; \
    KR0 = *(const short8*)&Kp[(rowQ + (size_t)((kt) * 64 + rr)) * 512 + colBase + cc]; \
    KR1 = *(const short8*)&Kp[(rowQ + (size_t)((kt) * 64 + rr + 32)) * 512 + colBase + cc]; \
    VR0 = *(const short8*)&Vh[(size_t)rr * 2048 + (kt) * 64 + cc]; \
    VR1 = *(const short8*)&Vh[(size_t)(rr + 32) * 2048 + (kt) * 64 + cc]; }

#define STG_WRITE(BUF, KR0, KR1, VR0, VR1) { \
    int rr = tid >> 3; \
    int sw = ((tid & 7) * 8) ^ ((rr & 7) << 3); \
    *(short8*)&Ks[BUF][rr * 64 + sw] = KR0; \
    *(short8*)&Ks[BUF][(rr + 32) * 64 + sw] = KR1; \
    *(short8*)&Vs[BUF][rr * 64 + sw] = VR0; \
    *(short8*)&Vs[BUF][(rr + 32) * 64 + sw] = VR1; }

__global__ __launch_bounds__(256, 3) void attn_kernel(
    const unsigned short* __restrict__ Q, const unsigned short* __restrict__ Kp,
    const unsigned short* __restrict__ Vt, unsigned short* __restrict__ O)
{
    const int tid = threadIdx.x, lane = tid & 63, wave = tid >> 6;
    const int lo = lane & 15, hi = lane >> 4;
    const int bh = blockIdx.x;
    const int qb = 31 - blockIdx.y;         // LPT: longest first
    const int bb = bh >> 3, hh = bh & 7;
    const int NT = qb + 1;

    __shared__ __align__(16) short Ks[2][64 * 64];
    __shared__ __align__(16) short Vs[2][64 * 64];
    __shared__ __align__(16) short P[4][16 * 72];
    short* Pw = P[wave];

    const size_t rowQ = (size_t)bb * 2048;
    const int colBase = hh * 64;
    const unsigned short* Vh = Vt + (size_t)bh * 64 * 2048;
    const int qrow = qb * 64 + wave * 16;

    short8 aq[2];
    #pragma unroll
    for (int s = 0; s < 2; ++s) {
        aq[s] = *(const short8*)&Q[(rowQ + qrow + lo) * 512 + colBase + s * 32 + hi * 8];
        #pragma unroll
        for (int e = 0; e < 8; ++e)   // fold softmax scale into Q (0.125 exact in bf16)
            aq[s][e] = (short)f2bfh(bf2f((unsigned short)aq[s][e]) * 0.125f);
    }

    f32x4 o_acc[4] = {};
    float m_i[4], l_i[4];
    #pragma unroll
    for (int r = 0; r < 4; ++r) { m_i[r] = -1e30f; l_i[r] = 0.0f; }

    short8 ka0, ka1, va0, va1;
    short8 kb0, kb1, vb0, vb1;

    STG_LOAD(0, ka0, ka1, va0, va1);
    STG_WRITE(0, ka0, ka1, va0, va1);
    if (1 < NT) STG_LOAD(1, kb0, kb1, vb0, vb1);
    __syncthreads();

    for (int kt = 0; kt < NT; ) {
        if (kt + 1 < NT) STG_WRITE(1, kb0, kb1, vb0, vb1);
        if (kt + 2 < NT) STG_LOAD(kt + 2, ka0, ka1, va0, va1);
        attn_step(kt, NT, qrow, lo, hi, Ks[0], Vs[0], Pw, aq, o_acc, m_i, l_i);
        __syncthreads();
        ++kt;
        if (kt >= NT) break;
        if (kt + 1 < NT) STG_WRITE(0, ka0, ka1, va0, va1);
        if (kt + 2 < NT) STG_LOAD(kt + 2, kb0, kb1, vb0, vb1);
        attn_step(kt, NT, qrow, lo, hi, Ks[1], Vs[1], Pw, aq, o_acc, m_i, l_i);
        __syncthreads();
        ++kt;
    }

    #pragma unroll
    for (int t = 0; t < 4; ++t)
        #pragma unroll
        for (int r = 0; r < 4; ++r) {
            float v = o_acc[t][r] / l_i[r];
            O[(rowQ + qrow + hi * 4 + r) * 512 + colBase + t * 16 + lo] = f2bfh(v);
        }
}

extern "C" void kernel_launch(void* const* d_in, const int* in_sizes, int n_in,
                              void* d_out, int out_size, void* d_ws, size_t ws_size,
                              hipStream_t stream)
{
    (void)in_sizes; (void)n_in; (void)out_size; (void)ws_size;
    const float* x   = (const float*)d_in[0];
    const float* w_q = (const float*)d_in[1];
    const float* w_k = (const float*)d_in[2];
    const float* w_v = (const float*)d_in[3];
    const float* ipw = (const float*)d_in[4];
    const float* ipb = (const float*)d_in[5];
    const float* ow  = (const float*)d_in[6];
    const float* ob  = (const float*)d_in[7];

    const int M = 16384;
    const size_t SZ = (size_t)M * 512;      // 8,388,608 elems
    // Workspace (~108 MB):
    //   xb [SZ] (reused as Qb) | wqb/wkb/wvb [3*256K] | ipwb [3*256K] | owb [256K]
    //   T [16384*1536] merged (first SZ reused as Cb) | Kb [SZ] | Vt [SZ] | ct/st [2*512K f32]
    unsigned short* xb   = (unsigned short*)d_ws;
    unsigned short* wqb  = xb + SZ;
    unsigned short* ipwb = wqb + 786432;
    unsigned short* owb  = ipwb + 786432;
    unsigned short* T    = owb + 262144;          // [16384][1536]
    unsigned short* Kb   = T + (size_t)M * 1536;
    unsigned short* Vt   = Kb + SZ;               // [64 bh][64 d][2048 m]
    float* ct = (float*)(Vt + SZ);
    float* st = ct + 524288;
    unsigned short* Qb   = xb;                    // reuse after stage 1
    unsigned short* Cb   = T;                     // reuse after stage 3

    dim3 blk(256);

    // Stage 0: conversions + rope table
    cvt_one<<<dim3((int)(SZ / 8 / 256)), blk, 0, stream>>>(x, xb, (int)(SZ / 8));
    cvt_w<<<dim3(128, 7), blk, 0, stream>>>(w_q, w_k, w_v, ipw, ow, wqb, ipwb, owb);
    rope_table<<<dim3(2048), blk, 0, stream>>>(ct, st);

    // Stage 1: T[16384,1536] = xb @ [wq;wk;wv]^T  (one merged GEMM)
    gemm_bt<0, 0><<<dim3(12, 128), blk, 0, stream>>>(xb, 512, wqb, nullptr, T, M, 1536, 512);

    // Stage 2: RoPE in-place (table-driven)
    rope_kernel<<<dim3(M), dim3(192), 0, stream>>>(T, ct, st);

    // Stage 3: grouped in_proj (Q,K row-major; V transposed)
    gemm_inproj<<<dim3(4, 128, 3), blk, 0, stream>>>(T, ipwb, ipb, Qb, Kb, Vt);

    // Stage 4: causal flash attention (LPT, XCD-local per bh)
    attn_kernel<<<dim3(64, 32), blk, 0, stream>>>(Qb, Kb, Vt, Cb);

    // Stage 5: output projection (f32 out)
    gemm_bt<1, 1><<<dim3(4, 128), blk, 0, stream>>>(Cb, 512, owb, ob, (float*)d_out, M, 512, 512);
}